// Round 2
// baseline (590.809 us; speedup 1.0000x reference)
//
#include <hip/hip_runtime.h>
#include <stdint.h>

#define K_TOP 10000
#define CAP   16384
#define N0    98304
#define N1    24576
#define N2    6144
#define N3    1536
#define N4    384
#define NROWS (K_TOP + K_TOP + N2 + N3 + N4)   // 28064
#define MAXGT 2048
#define RSUB  4     // sub-lanes per candidate in rank
#define ISUB  8     // sub-lanes per row in iou

struct SelState {
    unsigned hist[2][256];
    unsigned prefix[2];
    unsigned remK[2];
    unsigned candCount[2];
};

struct Ptrs {
    const float* anc[5];
    const float* cls[5];
    const float* reg[5];
};

// order-preserving float->uint map (ascending uint == ascending float)
__device__ __forceinline__ unsigned f2ord(float f) {
    unsigned u = __float_as_uint(f);
    return (u & 0x80000000u) ? ~u : (u | 0x80000000u);
}

__global__ void k_init(SelState* st) {
    int t = threadIdx.x;
    st->hist[0][t] = 0;
    st->hist[1][t] = 0;
    if (t < 2) { st->prefix[t] = 0; st->remK[t] = K_TOP; st->candCount[t] = 0; }
}

__global__ void k_hist(const float* __restrict__ cls0, const float* __restrict__ cls1,
                       SelState* st, int pass) {
    int lev = blockIdx.y;
    const float* cls = lev ? cls1 : cls0;
    int n = lev ? N1 : N0;
    __shared__ unsigned lh[256];
    lh[threadIdx.x] = 0;
    __syncthreads();
    unsigned prefix = st->prefix[lev];
    unsigned maskAbove = (pass == 0) ? 0u : (0xFFFFFFFFu << (32 - 8 * pass));
    int shift = 24 - 8 * pass;
    for (int i = blockIdx.x * blockDim.x + threadIdx.x; i < n; i += gridDim.x * blockDim.x) {
        unsigned key = f2ord(cls[i]);
        if ((key & maskAbove) == prefix)
            atomicAdd(&lh[(key >> shift) & 0xFFu], 1u);
    }
    __syncthreads();
    if (lh[threadIdx.x]) atomicAdd(&st->hist[lev][threadIdx.x], lh[threadIdx.x]);
}

__global__ void k_pick(SelState* st, int pass) {
    int lev = blockIdx.x;
    int t = threadIdx.x;
    __shared__ unsigned h[256];
    h[t] = st->hist[lev][t];
    st->hist[lev][t] = 0;           // reset for next pass
    __syncthreads();
    unsigned cum = 0;               // count of elements with digit > t (matching prefix)
    for (int e = t + 1; e < 256; e++) cum += h[e];
    unsigned remK = st->remK[lev];
    if (cum < remK && cum + h[t] >= remK) {   // unique digit
        st->remK[lev] = remK - cum;
        st->prefix[lev] |= ((unsigned)t) << (24 - 8 * pass);
    }
}

// T = 16-bit prefix (low 16 bits zero). Superset of top-K; rank pass makes order exact.
__global__ void k_compact(const float* __restrict__ cls0, const float* __restrict__ cls1,
                          SelState* st, unsigned long long* __restrict__ cand) {
    int lev = blockIdx.y;
    const float* cls = lev ? cls1 : cls0;
    int n = lev ? N1 : N0;
    unsigned T = st->prefix[lev];
    for (int i = blockIdx.x * blockDim.x + threadIdx.x; i < n; i += gridDim.x * blockDim.x) {
        unsigned key = f2ord(cls[i]);
        if (key >= T) {
            unsigned slot = atomicAdd(&st->candCount[lev], 1u);
            if (slot < CAP)
                cand[(size_t)lev * CAP + slot] =
                    ((unsigned long long)key << 32) | (unsigned)(~(unsigned)i);
        }
    }
}

// rank(i) = #{j : cand[j] > cand[i]}  (combined key: value desc, index asc)
// 4 sub-lanes per candidate, each counting a contiguous j-segment; shfl-sum.
__global__ void __launch_bounds__(256)
k_rank(SelState* st, const unsigned long long* __restrict__ cand,
       unsigned* __restrict__ selIdx) {
    int lev = blockIdx.y;
    unsigned cnt = st->candCount[lev];
    if (cnt > CAP) cnt = CAP;
    if (blockIdx.x * (256 / RSUB) >= cnt) return;   // block-uniform early exit
    unsigned gid = blockIdx.x * 256 + threadIdx.x;
    unsigned i = gid >> 2;
    unsigned s = gid & 3;
    unsigned long long ci = (i < cnt) ? cand[(size_t)lev * CAP + i] : 0ull;
    unsigned seg = (cnt + RSUB - 1) / RSUB;
    unsigned j0 = s * seg;
    unsigned j1 = j0 + seg; if (j1 > cnt) j1 = cnt;
    unsigned rank = 0;
    __shared__ unsigned long long tile[256];
    for (unsigned base = 0; base < cnt; base += 256) {
        unsigned j = base + threadIdx.x;
        tile[threadIdx.x] = (j < cnt) ? cand[(size_t)lev * CAP + j] : 0ull;
        __syncthreads();
        unsigned lim = base + 256; if (lim > cnt) lim = cnt;
        unsigned lo = (j0 > base) ? j0 : base;
        unsigned hi = (j1 < lim) ? j1 : lim;
        for (unsigned t = lo; t < hi; t++) rank += (tile[t - base] > ci) ? 1u : 0u;
        __syncthreads();
    }
    rank += __shfl_xor(rank, 1);
    rank += __shfl_xor(rank, 2);
    if (s == 0 && i < cnt && rank < K_TOP)
        selIdx[lev * K_TOP + rank] = ~(unsigned)ci;
}

__device__ __forceinline__ void row_to_level(int r, int& lev, int& base_r) {
    if (r < K_TOP)                        { lev = 0; base_r = 0; }
    else if (r < 2 * K_TOP)               { lev = 1; base_r = K_TOP; }
    else if (r < 2 * K_TOP + N2)          { lev = 2; base_r = 2 * K_TOP; }
    else if (r < 2 * K_TOP + N2 + N3)     { lev = 3; base_r = 2 * K_TOP + N2; }
    else                                  { lev = 4; base_r = 2 * K_TOP + N2 + N3; }
}

__global__ void __launch_bounds__(256)
k_decode(Ptrs p, const unsigned* __restrict__ selIdx,
         float* __restrict__ out, float4* __restrict__ boxws) {
    int r = blockIdx.x * blockDim.x + threadIdx.x;
    if (r >= NROWS) return;
    int lev, base_r;
    row_to_level(r, lev, base_r);
    int ai = (lev < 2) ? (int)selIdx[r] : (r - base_r);

    const float* A = p.anc[lev];
    const float* C = p.cls[lev];
    const float* R = p.reg[lev];

    float ax1 = A[ai * 4 + 0], ay1 = A[ai * 4 + 1];
    float ax2 = A[ai * 4 + 2], ay2 = A[ai * 4 + 3];
    float score = 1.0f / (1.0f + expf(-C[ai]));
    float d0 = R[ai * 8 + 0], d1 = R[ai * 8 + 1];
    float d2 = R[ai * 8 + 2], d3 = R[ai * 8 + 3];

    float w = ax2 - ax1 + 1.0f, h = ay2 - ay1 + 1.0f;
    float cx = ax1 + 0.5f * w,  cy = ay1 + 0.5f * h;
    float pcx = d0 * w + cx,    pcy = d1 * h + cy;
    float pw = expf(d2) * w,    ph = expf(d3) * h;
    float bx1 = pcx - 0.5f * pw, by1 = pcy - 0.5f * ph;
    float bx2 = pcx + 0.5f * pw - 1.0f, by2 = pcy + 0.5f * ph - 1.0f;

    float* o = out + (size_t)r * 10;
    o[0] = bx1; o[1] = by1; o[2] = bx2; o[3] = by2;
    o[4] = score; o[5] = 1.0f;
    boxws[r] = make_float4(bx1, by1, bx2, by2);
}

// 8 sub-lanes per row; each scans a contiguous GT chunk; exact first-max tie semantics.
__global__ void __launch_bounds__(256)
k_iou(Ptrs p, const unsigned* __restrict__ selIdx, const float4* __restrict__ boxws,
      const float* __restrict__ gt, const int* __restrict__ numgt,
      float* __restrict__ out) {
    __shared__ float4 sg[MAXGT];
    __shared__ float sarea[MAXGT];
    int ng = *numgt;
    if (ng > MAXGT) ng = MAXGT;
    for (int g = threadIdx.x; g < ng; g += blockDim.x) {
        float x1 = gt[g * 5 + 0], y1 = gt[g * 5 + 1];
        float x2 = gt[g * 5 + 2], y2 = gt[g * 5 + 3];
        sg[g] = make_float4(x1, y1, x2, y2);
        sarea[g] = (x2 - x1 + 1.0f) * (y2 - y1 + 1.0f);
    }
    __syncthreads();

    unsigned gid = blockIdx.x * 256 + threadIdx.x;
    int r = (int)(gid >> 3);
    int sub = (int)(gid & 7);
    if (r >= NROWS) return;

    float4 b = boxws[r];
    float areaA = (b.z - b.x + 1.0f) * (b.w - b.y + 1.0f);

    int cntper = (ng + ISUB - 1) / ISUB;
    int g0 = sub * cntper;
    int g1 = g0 + cntper; if (g1 > ng) g1 = ng;

    float best = -1.0f;
    int arg = 0x7FFFFFFF;
    for (int g = g0; g < g1; g++) {
        float4 gb = sg[g];
        float iw = fminf(b.z, gb.z) - fmaxf(b.x, gb.x) + 1.0f; iw = fmaxf(iw, 0.0f);
        float ih = fminf(b.w, gb.w) - fmaxf(b.y, gb.y) + 1.0f; ih = fmaxf(ih, 0.0f);
        float inter = iw * ih;
        float iou = inter / (areaA + sarea[g] - inter);
        if (iou > best) { best = iou; arg = g; }
    }
    // combine 8 partials: max iou, tie -> smallest index (== sequential first-max)
    for (int off = 1; off < 8; off <<= 1) {
        float ob = __shfl_xor(best, off);
        int   oa = __shfl_xor(arg, off);
        if (ob > best || (ob == best && oa < arg)) { best = ob; arg = oa; }
    }
    if (sub != 0) return;
    if (arg >= ng) arg = 0;   // safety (ng==0 can't happen here)

    int lev, base_r;
    row_to_level(r, lev, base_r);
    int ai = (lev < 2) ? (int)selIdx[r] : (r - base_r);
    const float* A = p.anc[lev];
    float ax1 = A[ai * 4 + 0], ay1 = A[ai * 4 + 1];
    float ax2 = A[ai * 4 + 2], ay2 = A[ai * 4 + 3];
    float w = ax2 - ax1 + 1.0f, h = ay2 - ay1 + 1.0f;
    float cx = ax1 + 0.5f * w,  cy = ay1 + 0.5f * h;

    float4 gb = sg[arg];
    float gw = gb.z - gb.x + 1.0f, gh = gb.w - gb.y + 1.0f;
    float gcx = gb.x + 0.5f * gw,  gcy = gb.y + 0.5f * gh;

    float* o = out + (size_t)r * 10;
    o[6] = (gcx - cx) / w;
    o[7] = (gcy - cy) / h;
    o[8] = logf(gw / w);
    o[9] = logf(gh / h);
}

extern "C" void kernel_launch(void* const* d_in, const int* in_sizes, int n_in,
                              void* d_out, int out_size, void* d_ws, size_t ws_size,
                              hipStream_t stream) {
    Ptrs p;
    bool interleaved = (in_sizes[2] == N0 * 8);
    for (int l = 0; l < 5; l++) {
        if (interleaved) {
            p.anc[l] = (const float*)d_in[3 * l + 0];
            p.cls[l] = (const float*)d_in[3 * l + 1];
            p.reg[l] = (const float*)d_in[3 * l + 2];
        } else {
            p.anc[l] = (const float*)d_in[l];
            p.cls[l] = (const float*)d_in[5 + l];
            p.reg[l] = (const float*)d_in[10 + l];
        }
    }
    const float* gt    = (const float*)d_in[15];
    const int*   numgt = (const int*)d_in[16];

    char* ws = (char*)d_ws;
    SelState* st = (SelState*)ws;                                     // 4 KiB
    unsigned long long* cand = (unsigned long long*)(ws + 4096);      // 256 KiB
    unsigned* selIdx = (unsigned*)(ws + 4096 + 2 * (size_t)CAP * 8);  // 80 KiB
    float4* boxws = (float4*)(ws + 4096 + 2 * (size_t)CAP * 8 + 81920); // 449 KiB

    float* out = (float*)d_out;

    k_init<<<dim3(1), dim3(256), 0, stream>>>(st);
    for (int pass = 0; pass < 2; pass++) {
        k_hist<<<dim3(64, 2), dim3(256), 0, stream>>>(p.cls[0], p.cls[1], st, pass);
        k_pick<<<dim3(2), dim3(256), 0, stream>>>(st, pass);
    }
    k_compact<<<dim3(96, 2), dim3(256), 0, stream>>>(p.cls[0], p.cls[1], st, cand);
    k_rank<<<dim3(CAP / (256 / RSUB), 2), dim3(256), 0, stream>>>(st, cand, selIdx);
    k_decode<<<dim3((NROWS + 255) / 256), dim3(256), 0, stream>>>(p, selIdx, out, boxws);
    k_iou<<<dim3((NROWS * ISUB + 255) / 256), dim3(256), 0, stream>>>(p, selIdx, boxws, gt, numgt, out);
}

// Round 3
// 142.098 us; speedup vs baseline: 4.1578x; 4.1578x over previous
//
#include <hip/hip_runtime.h>
#include <stdint.h>

#define K_TOP 10000
#define CAP   16384
#define N0    98304
#define N1    24576
#define N2    6144
#define N3    1536
#define N4    384
#define NROWS (K_TOP + K_TOP + N2 + N3 + N4)   // 28064
#define MAXGT 2048
#define ISUB  8      // sub-lanes per row in iou (equal trip counts -> no divergence)
#define JSPLIT 16    // j-chunks in rank partials
#define RBLK  1024   // candidates per rank block (256 threads x 4 regs)

struct SelState {
    unsigned hist[2][256];
    unsigned prefix[2];
    unsigned remK[2];
    unsigned candCount[2];
};

struct Ptrs {
    const float* anc[5];
    const float* cls[5];
    const float* reg[5];
};

// order-preserving float->uint map (ascending uint == ascending float)
__device__ __forceinline__ unsigned f2ord(float f) {
    unsigned u = __float_as_uint(f);
    return (u & 0x80000000u) ? ~u : (u | 0x80000000u);
}

__global__ void k_init(SelState* st) {
    int t = threadIdx.x;
    st->hist[0][t] = 0;
    st->hist[1][t] = 0;
    if (t < 2) { st->prefix[t] = 0; st->remK[t] = K_TOP; st->candCount[t] = 0; }
}

__global__ void k_hist(const float* __restrict__ cls0, const float* __restrict__ cls1,
                       SelState* st, int pass) {
    int lev = blockIdx.y;
    const float* cls = lev ? cls1 : cls0;
    int n = lev ? N1 : N0;
    __shared__ unsigned lh[256];
    lh[threadIdx.x] = 0;
    __syncthreads();
    unsigned prefix = st->prefix[lev];
    unsigned maskAbove = (pass == 0) ? 0u : (0xFFFFFFFFu << (32 - 8 * pass));
    int shift = 24 - 8 * pass;
    for (int i = blockIdx.x * blockDim.x + threadIdx.x; i < n; i += gridDim.x * blockDim.x) {
        unsigned key = f2ord(cls[i]);
        if ((key & maskAbove) == prefix)
            atomicAdd(&lh[(key >> shift) & 0xFFu], 1u);
    }
    __syncthreads();
    if (lh[threadIdx.x]) atomicAdd(&st->hist[lev][threadIdx.x], lh[threadIdx.x]);
}

__global__ void k_pick(SelState* st, int pass) {
    int lev = blockIdx.x;
    int t = threadIdx.x;
    __shared__ unsigned h[256];
    h[t] = st->hist[lev][t];
    st->hist[lev][t] = 0;           // reset for next pass
    __syncthreads();
    unsigned cum = 0;               // count of elements with digit > t (matching prefix)
    for (int e = t + 1; e < 256; e++) cum += h[e];
    unsigned remK = st->remK[lev];
    if (cum < remK && cum + h[t] >= remK) {   // unique crossing digit
        st->remK[lev] = remK - cum;
        st->prefix[lev] |= ((unsigned)t) << (24 - 8 * pass);
    }
}

// T = 16-bit prefix threshold. Superset of top-K; rank pass makes order exact.
__global__ void k_compact(const float* __restrict__ cls0, const float* __restrict__ cls1,
                          SelState* st, unsigned long long* __restrict__ cand) {
    int lev = blockIdx.y;
    const float* cls = lev ? cls1 : cls0;
    int n = lev ? N1 : N0;
    unsigned T = st->prefix[lev];
    for (int i = blockIdx.x * blockDim.x + threadIdx.x; i < n; i += gridDim.x * blockDim.x) {
        unsigned key = f2ord(cls[i]);
        if (key >= T) {
            unsigned slot = atomicAdd(&st->candCount[lev], 1u);
            if (slot < CAP)
                cand[(size_t)lev * CAP + slot] =
                    ((unsigned long long)key << 32) | (unsigned)(~(unsigned)i);
        }
    }
}

// Partial counting-rank: block (bx,by,lev). bx owns RBLK candidates in regs,
// by owns one j-chunk. Uniform bounds; tile[t] broadcast; 4 cmp per ds_read.
__global__ void __launch_bounds__(256)
k_rankpart(SelState* st, const unsigned long long* __restrict__ cand,
           unsigned short* __restrict__ part) {
    int lev = blockIdx.z;
    unsigned cnt = st->candCount[lev];
    if (cnt > CAP) cnt = CAP;
    unsigned ibase = blockIdx.x * RBLK;
    if (ibase >= cnt) return;                     // block-uniform
    unsigned jchunk = (cnt + JSPLIT - 1) / JSPLIT;
    unsigned j0 = blockIdx.y * jchunk;
    unsigned j1 = j0 + jchunk; if (j1 > cnt) j1 = cnt;

    unsigned long long ci[4];
    #pragma unroll
    for (int c = 0; c < 4; c++) {
        unsigned i = ibase + threadIdx.x + c * 256;
        ci[c] = (i < cnt) ? cand[(size_t)lev * CAP + i] : 0xFFFFFFFFFFFFFFFFull;
    }
    unsigned rk0 = 0, rk1 = 0, rk2 = 0, rk3 = 0;
    __shared__ unsigned long long tile[256];
    for (unsigned base = j0; base < j1; base += 256) {
        unsigned j = base + threadIdx.x;
        tile[threadIdx.x] = (j < j1) ? cand[(size_t)lev * CAP + j] : 0ull;
        __syncthreads();
        unsigned lim = j1 - base; if (lim > 256u) lim = 256u;   // block-uniform
        #pragma unroll 4
        for (unsigned t = 0; t < lim; t++) {
            unsigned long long cj = tile[t];
            rk0 += (cj > ci[0]) ? 1u : 0u;
            rk1 += (cj > ci[1]) ? 1u : 0u;
            rk2 += (cj > ci[2]) ? 1u : 0u;
            rk3 += (cj > ci[3]) ? 1u : 0u;
        }
        __syncthreads();
    }
    unsigned short* pp = part + ((size_t)(lev * JSPLIT + blockIdx.y)) * CAP;
    unsigned i0 = ibase + threadIdx.x;
    pp[i0]       = (unsigned short)rk0;
    pp[i0 + 256] = (unsigned short)rk1;
    pp[i0 + 512] = (unsigned short)rk2;
    pp[i0 + 768] = (unsigned short)rk3;
}

__global__ void __launch_bounds__(256)
k_scatter(SelState* st, const unsigned long long* __restrict__ cand,
          const unsigned short* __restrict__ part, unsigned* __restrict__ selIdx) {
    int lev = blockIdx.y;
    unsigned cnt = st->candCount[lev];
    if (cnt > CAP) cnt = CAP;
    unsigned i = blockIdx.x * 256 + threadIdx.x;
    if (i >= cnt) return;
    unsigned rank = 0;
    #pragma unroll
    for (int s = 0; s < JSPLIT; s++)
        rank += part[((size_t)(lev * JSPLIT + s)) * CAP + i];
    if (rank < K_TOP)
        selIdx[lev * K_TOP + rank] = ~(unsigned)cand[(size_t)lev * CAP + i];
}

__device__ __forceinline__ void row_to_level(int r, int& lev, int& base_r) {
    if (r < K_TOP)                        { lev = 0; base_r = 0; }
    else if (r < 2 * K_TOP)               { lev = 1; base_r = K_TOP; }
    else if (r < 2 * K_TOP + N2)          { lev = 2; base_r = 2 * K_TOP; }
    else if (r < 2 * K_TOP + N2 + N3)     { lev = 3; base_r = 2 * K_TOP + N2; }
    else                                  { lev = 4; base_r = 2 * K_TOP + N2 + N3; }
}

__global__ void __launch_bounds__(256)
k_decode(Ptrs p, const unsigned* __restrict__ selIdx,
         float* __restrict__ out, float4* __restrict__ boxws) {
    int r = blockIdx.x * blockDim.x + threadIdx.x;
    if (r >= NROWS) return;
    int lev, base_r;
    row_to_level(r, lev, base_r);
    int ai = (lev < 2) ? (int)selIdx[r] : (r - base_r);

    const float* A = p.anc[lev];
    const float* C = p.cls[lev];
    const float* R = p.reg[lev];

    float ax1 = A[ai * 4 + 0], ay1 = A[ai * 4 + 1];
    float ax2 = A[ai * 4 + 2], ay2 = A[ai * 4 + 3];
    float score = 1.0f / (1.0f + expf(-C[ai]));
    float d0 = R[ai * 8 + 0], d1 = R[ai * 8 + 1];
    float d2 = R[ai * 8 + 2], d3 = R[ai * 8 + 3];

    float w = ax2 - ax1 + 1.0f, h = ay2 - ay1 + 1.0f;
    float cx = ax1 + 0.5f * w,  cy = ay1 + 0.5f * h;
    float pcx = d0 * w + cx,    pcy = d1 * h + cy;
    float pw = expf(d2) * w,    ph = expf(d3) * h;
    float bx1 = pcx - 0.5f * pw, by1 = pcy - 0.5f * ph;
    float bx2 = pcx + 0.5f * pw - 1.0f, by2 = pcy + 0.5f * ph - 1.0f;

    float* o = out + (size_t)r * 10;
    o[0] = bx1; o[1] = by1; o[2] = bx2; o[3] = by2;
    o[4] = score; o[5] = 1.0f;
    boxws[r] = make_float4(bx1, by1, bx2, by2);
}

// 8 sub-lanes per row; equal trip counts (no divergent-bounds serialization).
__global__ void __launch_bounds__(256)
k_iou(Ptrs p, const unsigned* __restrict__ selIdx, const float4* __restrict__ boxws,
      const float* __restrict__ gt, const int* __restrict__ numgt,
      float* __restrict__ out) {
    __shared__ float4 sg[MAXGT];
    __shared__ float sarea[MAXGT];
    int ng = *numgt;
    if (ng > MAXGT) ng = MAXGT;
    for (int g = threadIdx.x; g < ng; g += blockDim.x) {
        float x1 = gt[g * 5 + 0], y1 = gt[g * 5 + 1];
        float x2 = gt[g * 5 + 2], y2 = gt[g * 5 + 3];
        sg[g] = make_float4(x1, y1, x2, y2);
        sarea[g] = (x2 - x1 + 1.0f) * (y2 - y1 + 1.0f);
    }
    __syncthreads();

    unsigned gid = blockIdx.x * 256 + threadIdx.x;
    int r = (int)(gid >> 3);
    int sub = (int)(gid & 7);
    if (r >= NROWS) return;

    float4 b = boxws[r];
    float areaA = (b.z - b.x + 1.0f) * (b.w - b.y + 1.0f);

    int cntper = (ng + ISUB - 1) / ISUB;
    int g0 = sub * cntper;
    int g1 = g0 + cntper; if (g1 > ng) g1 = ng;

    float best = -1.0f;
    int arg = 0x7FFFFFFF;
    for (int g = g0; g < g1; g++) {
        float4 gb = sg[g];
        float iw = fminf(b.z, gb.z) - fmaxf(b.x, gb.x) + 1.0f; iw = fmaxf(iw, 0.0f);
        float ih = fminf(b.w, gb.w) - fmaxf(b.y, gb.y) + 1.0f; ih = fmaxf(ih, 0.0f);
        float inter = iw * ih;
        float iou = inter / (areaA + sarea[g] - inter);
        if (iou > best) { best = iou; arg = g; }
    }
    // combine 8 partials: max iou, tie -> smallest index (== sequential first-max)
    for (int off = 1; off < 8; off <<= 1) {
        float ob = __shfl_xor(best, off);
        int   oa = __shfl_xor(arg, off);
        if (ob > best || (ob == best && oa < arg)) { best = ob; arg = oa; }
    }
    if (sub != 0) return;
    if (arg >= ng) arg = 0;

    int lev, base_r;
    row_to_level(r, lev, base_r);
    int ai = (lev < 2) ? (int)selIdx[r] : (r - base_r);
    const float* A = p.anc[lev];
    float ax1 = A[ai * 4 + 0], ay1 = A[ai * 4 + 1];
    float ax2 = A[ai * 4 + 2], ay2 = A[ai * 4 + 3];
    float w = ax2 - ax1 + 1.0f, h = ay2 - ay1 + 1.0f;
    float cx = ax1 + 0.5f * w,  cy = ay1 + 0.5f * h;

    float4 gb = sg[arg];
    float gw = gb.z - gb.x + 1.0f, gh = gb.w - gb.y + 1.0f;
    float gcx = gb.x + 0.5f * gw,  gcy = gb.y + 0.5f * gh;

    float* o = out + (size_t)r * 10;
    o[6] = (gcx - cx) / w;
    o[7] = (gcy - cy) / h;
    o[8] = logf(gw / w);
    o[9] = logf(gh / h);
}

extern "C" void kernel_launch(void* const* d_in, const int* in_sizes, int n_in,
                              void* d_out, int out_size, void* d_ws, size_t ws_size,
                              hipStream_t stream) {
    Ptrs p;
    bool interleaved = (in_sizes[2] == N0 * 8);
    for (int l = 0; l < 5; l++) {
        if (interleaved) {
            p.anc[l] = (const float*)d_in[3 * l + 0];
            p.cls[l] = (const float*)d_in[3 * l + 1];
            p.reg[l] = (const float*)d_in[3 * l + 2];
        } else {
            p.anc[l] = (const float*)d_in[l];
            p.cls[l] = (const float*)d_in[5 + l];
            p.reg[l] = (const float*)d_in[10 + l];
        }
    }
    const float* gt    = (const float*)d_in[15];
    const int*   numgt = (const int*)d_in[16];

    char* ws = (char*)d_ws;
    size_t off = 0;
    SelState* st = (SelState*)(ws + off);                 off += 4096;
    unsigned long long* cand = (unsigned long long*)(ws + off); off += (size_t)2 * CAP * 8;      // 256 KiB
    unsigned* selIdx = (unsigned*)(ws + off);             off += (size_t)2 * K_TOP * 4 + 2048;   // 80 KiB
    unsigned short* part = (unsigned short*)(ws + off);   off += (size_t)2 * JSPLIT * CAP * 2;   // 1 MiB
    float4* boxws = (float4*)(ws + off);                  off += (size_t)NROWS * 16;             // 449 KiB

    float* out = (float*)d_out;

    k_init<<<dim3(1), dim3(256), 0, stream>>>(st);
    for (int pass = 0; pass < 2; pass++) {
        k_hist<<<dim3(64, 2), dim3(256), 0, stream>>>(p.cls[0], p.cls[1], st, pass);
        k_pick<<<dim3(2), dim3(256), 0, stream>>>(st, pass);
    }
    k_compact<<<dim3(96, 2), dim3(256), 0, stream>>>(p.cls[0], p.cls[1], st, cand);
    k_rankpart<<<dim3(CAP / RBLK, JSPLIT, 2), dim3(256), 0, stream>>>(st, cand, part);
    k_scatter<<<dim3(CAP / 256, 2), dim3(256), 0, stream>>>(st, cand, part, selIdx);
    k_decode<<<dim3((NROWS + 255) / 256), dim3(256), 0, stream>>>(p, selIdx, out, boxws);
    k_iou<<<dim3((NROWS * ISUB + 255) / 256), dim3(256), 0, stream>>>(p, selIdx, boxws, gt, numgt, out);
}